// Round 1
// baseline (85.416 us; speedup 1.0000x reference)
//
#include <hip/hip_runtime.h>
#include <math.h>

#define NB 64      // batch
#define NN 256     // elements per batch
#define NPAIRS 32640.0f   // N*(N-1)/2
#define EPSF 1e-8f

// ws layout (floats):
//   per-batch  [11][64]  at 0    : 0 noise,1 posmse,2 iou,3 layermse,4 conf,
//                                  5 golden,6 areaSum,7 area2Sum,8 cxSum,9 cySum,10 vc
//   per-block  [3][256]  at 704  : 0 rank, 1 overlap, 2 align
#define PB(q) ((q) * 64)
#define PW(q) (704 + (q) * 256)

// Block-wide sum for 256 threads (4 waves of 64). Result valid on ALL threads
// after return. Safe for back-to-back calls (sync discipline below).
__device__ __forceinline__ float block_sum(float v, float* sred) {
    const int tid = threadIdx.x;
    #pragma unroll
    for (int off = 32; off > 0; off >>= 1) v += __shfl_down(v, off, 64);
    __syncthreads();                 // previous readers of sred are done
    if ((tid & 63) == 0) sred[tid >> 6] = v;
    __syncthreads();
    return sred[0] + sred[1] + sred[2] + sred[3];
}

__global__ __launch_bounds__(256) void loss_main(
    const float* __restrict__ pn, const float* __restrict__ tn,
    const float* __restrict__ pl, const float* __restrict__ tl,
    const float* __restrict__ mask, float* __restrict__ ws)
{
    __shared__ float sx1[NN], sy1[NN], sx2[NN], sy2[NN], scx[NN], scy[NN],
                     sar[NN], spl[NN], stl[NN], sm[NN];
    __shared__ float sred[4];

    const int b     = blockIdx.x >> 2;   // batch
    const int chunk = blockIdx.x & 3;    // pair-distance chunk
    const int i     = threadIdx.x;       // element within batch
    const int e     = b * NN + i;
    const float m   = mask[e];
    const int base  = e * 6;

    // masked layout fields (pl/tl * mask, faithful to reference)
    const float p0 = pl[base + 0] * m, p1 = pl[base + 1] * m,
                p2 = pl[base + 2] * m, p3 = pl[base + 3] * m,
                p4 = pl[base + 4] * m, p5 = pl[base + 5] * m;
    const float t0 = tl[base + 0] * m, t1 = tl[base + 1] * m,
                t2 = tl[base + 2] * m, t3 = tl[base + 3] * m,
                t4 = tl[base + 4] * m, t5 = tl[base + 5] * m;

    const float x2v = p0 + p2, y2v = p1 + p3;
    const float areav = p2 * p3;                 // w*h (mask applied later for aesthetics)
    const float cxe = p0 + 0.5f * p2, cye = p1 + 0.5f * p3;

    sx1[i] = p0;  sy1[i] = p1;  sx2[i] = x2v;  sy2[i] = y2v;
    scx[i] = cxe; scy[i] = cye; sar[i] = areav;
    spl[i] = p4;  stl[i] = t4;  sm[i]  = m;
    __syncthreads();

    // ---------------- elementwise terms ----------------
    float noise = 0.f;
    #pragma unroll
    for (int k = 0; k < 6; ++k) {
        float d = fabsf(pn[base + k] * m - tn[base + k] * m);
        noise += (d < 1.f) ? 0.5f * d * d : d - 0.5f;
    }
    float posmse = (p0 - t0) * (p0 - t0) + (p1 - t1) * (p1 - t1)
                 + (p2 - t2) * (p2 - t2) + (p3 - t3) * (p3 - t3);
    // IoU (pred vs target boxes)
    const float tx2 = t0 + t2, ty2 = t1 + t3;
    float iw = fmaxf(fminf(x2v, tx2) - fmaxf(p0, t0), 0.f);
    float ih = fmaxf(fminf(y2v, ty2) - fmaxf(p1, t1), 0.f);
    float inter = iw * ih;
    float iouL = 1.f - inter / (p2 * p3 + t2 * t3 - inter + EPSF);
    float lmse = (p4 - t4) * (p4 - t4);
    float cmse = (p5 - t5) * (p5 - t5);
    float golden = fabsf(p2 / (p3 + EPSF) - 1.618f);
    float areaA = areav * m;                 // areas = w*h*mask
    float cxA = cxe * m, cyA = cye * m;      // centers * mask

    // ---------------- pairwise terms (this chunk's dd range) ----------------
    float rank = 0.f, ovl = 0.f, aln = 0.f;
    const int dd0 = chunk * 32 + 1;
    for (int dd = dd0; dd < dd0 + 32; ++dd) {
        int j = (i + dd) & 255;
        if (dd == 128 && i >= 128) continue;   // dd=128 pairs counted once (i<j)
        float x1j = sx1[j], y1j = sy1[j], x2j = sx2[j], y2j = sy2[j];
        float cxj = scx[j], cyj = scy[j], arj = sar[j];
        float plj = spl[j], tlj = stl[j], mj = sm[j];
        float pv = m * mj;
        // overlap
        float ow = fmaxf(fminf(x2v, x2j) - fmaxf(p0, x1j), 0.f);
        float oh = fmaxf(fminf(y2v, y2j) - fmaxf(p1, y1j), 0.f);
        ovl += ow * oh / (fminf(areav, arj) + EPSF) * pv;
        // alignment (6 edge types, dist<5 -> dist/5)
        float pen = 0.f, d;
        d = fabsf(p0  - x1j); pen += (d < 5.f) ? d : 0.f;
        d = fabsf(x2v - x2j); pen += (d < 5.f) ? d : 0.f;
        d = fabsf(p1  - y1j); pen += (d < 5.f) ? d : 0.f;
        d = fabsf(y2v - y2j); pen += (d < 5.f) ? d : 0.f;
        d = fabsf(cxe - cxj); pen += (d < 5.f) ? d : 0.f;
        d = fabsf(cye - cyj); pen += (d < 5.f) ? d : 0.f;
        aln += pen * 0.2f * pv;
        // ranking BCE on ordered (lo,hi)=(min(i,j),max(i,j)): diff = p[hi]-p[lo]
        bool ilt = (i < j);
        float dlo = ilt ? (plj - p4) : (p4 - plj);
        float ylo = (ilt ? (t4 < tlj) : (tlj < t4)) ? 1.f : 0.f;
        float sp  = log1pf(expf(-fabsf(dlo)));          // stable softplus core
        float sp_pos = sp + fmaxf(dlo, 0.f);            // softplus(+diff)
        float sp_neg = sp + fmaxf(-dlo, 0.f);           // softplus(-diff)
        rank += ylo * fminf(sp_neg, 100.f) + (1.f - ylo) * fminf(sp_pos, 100.f);
    }

    // ---------------- reductions & stores ----------------
    // per-batch sums: all 4 chunk-blocks compute identical values; duplicate
    // same-value stores to ws[PB(q)+b] are benign.
    float s;
    s = block_sum(noise,  sred); if (i == 0) ws[PB(0)  + b] = s;
    s = block_sum(posmse, sred); if (i == 0) ws[PB(1)  + b] = s;
    s = block_sum(iouL,   sred); if (i == 0) ws[PB(2)  + b] = s;
    s = block_sum(lmse,   sred); if (i == 0) ws[PB(3)  + b] = s;
    s = block_sum(cmse,   sred); if (i == 0) ws[PB(4)  + b] = s;
    s = block_sum(golden, sred); if (i == 0) ws[PB(5)  + b] = s;
    s = block_sum(areaA,  sred); if (i == 0) ws[PB(6)  + b] = s;
    s = block_sum(areaA * areaA, sred); if (i == 0) ws[PB(7) + b] = s;
    s = block_sum(cxA,    sred); if (i == 0) ws[PB(8)  + b] = s;
    s = block_sum(cyA,    sred); if (i == 0) ws[PB(9)  + b] = s;
    s = block_sum(m,      sred); if (i == 0) ws[PB(10) + b] = s;
    // per-block pairwise sums
    s = block_sum(rank, sred); if (i == 0) ws[PW(0) + blockIdx.x] = s;
    s = block_sum(ovl,  sred); if (i == 0) ws[PW(1) + blockIdx.x] = s;
    s = block_sum(aln,  sred); if (i == 0) ws[PW(2) + blockIdx.x] = s;
}

__global__ __launch_bounds__(256) void loss_final(
    const float* __restrict__ ws, float* __restrict__ out)
{
    __shared__ float sred[4];
    __shared__ float bcx[NB], bcy[NB], bvc[NB];
    const int t = threadIdx.x;

    float v_noise = 0.f, v_pos = 0.f, v_iou = 0.f, v_lm = 0.f, v_cf = 0.f,
          v_go = 0.f, v_ar = 0.f, v_std = 0.f;
    if (t < NB) {
        v_noise = ws[PB(0) + t];
        v_pos   = ws[PB(1) + t];
        v_iou   = ws[PB(2) + t];
        v_lm    = ws[PB(3) + t];
        v_cf    = ws[PB(4) + t];
        v_go    = ws[PB(5) + t];
        v_ar    = ws[PB(6) + t];
        float a2 = ws[PB(7) + t];
        // per-row std, ddof=1:  sqrt( (sum(a^2) - (sum a)^2/N) / (N-1) )
        float var = (a2 - v_ar * v_ar * (1.f / 256.f)) * (1.f / 255.f);
        v_std = sqrtf(fmaxf(var, 0.f));
        bcx[t] = ws[PB(8) + t];
        bcy[t] = ws[PB(9) + t];
        bvc[t] = ws[PB(10) + t];
    }
    float v_rank = ws[PW(0) + t];
    float v_ovl  = ws[PW(1) + t];
    float v_aln  = ws[PW(2) + t];
    __syncthreads();

    // faithful [B,B] balance broadcast: ocx[i,j] = sumcx[j]/(vc[i]+EPS)
    float v_bal = 0.f;
    if (t < NB) {
        float inv = 1.f / (bvc[t] + EPSF);
        for (int j = 0; j < NB; ++j) {
            v_bal += fabsf(bcx[j] * inv - 512.f) * (1.f / 512.f)
                   + fabsf(bcy[j] * inv - 512.f) * (1.f / 512.f);
        }
    }

    float S_noise = block_sum(v_noise, sred);
    float S_pos   = block_sum(v_pos,   sred);
    float S_iou   = block_sum(v_iou,   sred);
    float S_lm    = block_sum(v_lm,    sred);
    float S_cf    = block_sum(v_cf,    sred);
    float S_go    = block_sum(v_go,    sred);
    float S_ar    = block_sum(v_ar,    sred);
    float S_std   = block_sum(v_std,   sred);
    float S_bal   = block_sum(v_bal,   sred);
    float S_rank  = block_sum(v_rank,  sred);
    float S_ovl   = block_sum(v_ovl,   sred);
    float S_aln   = block_sum(v_aln,   sred);

    if (t == 0) {
        const float BN = 64.f * 256.f;
        float noise_loss = S_noise / (BN * 6.f);
        float position   = S_pos / (BN * 4.f) + 0.5f * (S_iou / BN);
        float layer      = S_lm / BN + 0.3f * (S_rank / (64.f * NPAIRS));
        float conf       = S_cf / BN;
        float golden     = S_go / BN;
        float size_harm  = (S_std / 64.f) / (S_ar / BN + EPSF);
        float balance    = S_bal / 4096.f;
        float aes        = 0.1f * golden + 0.2f * size_harm + 0.15f * balance;
        float ovl        = S_ovl / (64.f * NPAIRS);
        float aln        = S_aln / (64.f * 6.f * NPAIRS);
        out[0] = noise_loss + position + 0.5f * layer + 0.3f * conf
               + 0.2f * aes + 0.8f * ovl + 0.4f * aln;
    }
}

extern "C" void kernel_launch(void* const* d_in, const int* in_sizes, int n_in,
                              void* d_out, int out_size, void* d_ws, size_t ws_size,
                              hipStream_t stream) {
    const float* pn   = (const float*)d_in[0];
    const float* tn   = (const float*)d_in[1];
    const float* pl   = (const float*)d_in[2];
    const float* tl   = (const float*)d_in[3];
    const float* mask = (const float*)d_in[4];
    float* ws  = (float*)d_ws;
    float* out = (float*)d_out;
    hipLaunchKernelGGL(loss_main, dim3(256), dim3(256), 0, stream,
                       pn, tn, pl, tl, mask, ws);
    hipLaunchKernelGGL(loss_final, dim3(1), dim3(256), 0, stream, ws, out);
}

// Round 2
// 75.863 us; speedup vs baseline: 1.1259x; 1.1259x over previous
//
#include <hip/hip_runtime.h>
#include <math.h>

#define NB 64      // batch
#define NN 256     // elements per batch
#define NPAIRS 32640.0f   // N*(N-1)/2
#define EPSF 1e-8f

// ws layout (floats):
//   per-batch  [11][64]  at 0    : 0 noise,1 posmse,2 iou,3 layermse,4 conf,
//                                  5 golden,6 areaSum,7 area2Sum,8 cxSum,9 cySum,10 vc
//   per-block  [3][256]  at 704  : 0 rank, 1 overlap, 2 align
#define PB(q) ((q) * 64)
#define PW(q) (704 + (q) * 256)

// Block-wide sum for 256 threads (4 waves of 64). Result valid on ALL threads.
__device__ __forceinline__ float block_sum(float v, float* sred) {
    const int tid = threadIdx.x;
    #pragma unroll
    for (int off = 32; off > 0; off >>= 1) v += __shfl_down(v, off, 64);
    __syncthreads();                 // previous readers of sred are done
    if ((tid & 63) == 0) sred[tid >> 6] = v;
    __syncthreads();
    return sred[0] + sred[1] + sred[2] + sred[3];
}

__global__ __launch_bounds__(256) void loss_main(
    const float* __restrict__ pn, const float* __restrict__ tn,
    const float* __restrict__ pl, const float* __restrict__ tl,
    const float* __restrict__ mask, float* __restrict__ ws)
{
    // packed pair fields: sA = {x1, y1, x2, y2}, sB = {cx, cy, area, p_layer},
    // sC = {t_layer, m}
    __shared__ float4 sA[NN], sB[NN];
    __shared__ float2 sC[NN];
    __shared__ float sred[4];

    const int b     = blockIdx.x >> 2;   // batch
    const int chunk = blockIdx.x & 3;    // pair-distance chunk / scalar-duty chunk
    const int i     = threadIdx.x;       // element within batch
    const int e     = b * NN + i;
    const float m   = mask[e];

    // vectorized row loads (rows are 24B-aligned -> float2 ok)
    const float2* pl2 = (const float2*)pl;
    const float2* tl2 = (const float2*)tl;
    const int r2 = e * 3;
    const float2 pla = pl2[r2 + 0], plb = pl2[r2 + 1], plc = pl2[r2 + 2];
    const float2 tlc = tl2[r2 + 2];

    const float p0 = pla.x * m, p1 = pla.y * m,
                p2 = plb.x * m, p3 = plb.y * m,
                p4 = plc.x * m, p5 = plc.y * m;
    const float t4 = tlc.x * m, t5 = tlc.y * m;

    const float x2v = p0 + p2, y2v = p1 + p3;
    const float areav = p2 * p3;
    const float cxe = p0 + 0.5f * p2, cye = p1 + 0.5f * p3;

    sA[i] = make_float4(p0, p1, x2v, y2v);
    sB[i] = make_float4(cxe, cye, areav, p4);
    sC[i] = make_float2(t4, m);
    __syncthreads();

    // ---------------- pairwise terms (this chunk's dd range) ----------------
    float rank = 0.f, ovl = 0.f, aln = 0.f;
    const int dd0 = chunk * 32 + 1;
    #pragma unroll 4
    for (int dd = dd0; dd < dd0 + 32; ++dd) {
        int j = (i + dd) & 255;
        if (dd == 128 && i >= 128) continue;   // dd=128 pairs counted once (i<j)
        float4 aj = sA[j];
        float4 bj = sB[j];
        float2 cj = sC[j];
        float pv = m * cj.y;
        // overlap
        float ow = fmaxf(fminf(x2v, aj.z) - fmaxf(p0, aj.x), 0.f);
        float oh = fmaxf(fminf(y2v, aj.w) - fmaxf(p1, aj.y), 0.f);
        ovl += ow * oh / (fminf(areav, bj.z) + EPSF) * pv;
        // alignment (6 edge types, dist<5 -> dist/5; /5 folded into 0.2f)
        float pen = 0.f, d;
        d = fabsf(p0  - aj.x); pen += (d < 5.f) ? d : 0.f;
        d = fabsf(x2v - aj.z); pen += (d < 5.f) ? d : 0.f;
        d = fabsf(p1  - aj.y); pen += (d < 5.f) ? d : 0.f;
        d = fabsf(y2v - aj.w); pen += (d < 5.f) ? d : 0.f;
        d = fabsf(cxe - bj.x); pen += (d < 5.f) ? d : 0.f;
        d = fabsf(cye - bj.y); pen += (d < 5.f) ? d : 0.f;
        aln += pen * 0.2f * pv;
        // ranking BCE on ordered (lo,hi)=(min(i,j),max(i,j)): diff = p[hi]-p[lo]
        bool ilt = (i < j);
        float dlo = ilt ? (bj.w - p4) : (p4 - bj.w);
        float ylo = (ilt ? (t4 < cj.x) : (cj.x < t4)) ? 1.f : 0.f;
        float sp  = __logf(1.f + __expf(-fabsf(dlo)));   // stable softplus core
        float sp_pos = sp + fmaxf(dlo, 0.f);             // softplus(+diff)
        float sp_neg = sp + fmaxf(-dlo, 0.f);            // softplus(-diff)
        rank += ylo * fminf(sp_neg, 100.f) + (1.f - ylo) * fminf(sp_pos, 100.f);
    }

    // pairwise per-block sums (all chunks)
    float s;
    s = block_sum(rank, sred); if (i == 0) ws[PW(0) + blockIdx.x] = s;
    s = block_sum(ovl,  sred); if (i == 0) ws[PW(1) + blockIdx.x] = s;
    s = block_sum(aln,  sred); if (i == 0) ws[PW(2) + blockIdx.x] = s;

    // ---------------- elementwise terms: distributed across chunks ----------
    if (chunk == 0) {
        // noise SmoothL1 (only this chunk touches pn/tn)
        const float2* pn2 = (const float2*)pn;
        const float2* tn2 = (const float2*)tn;
        float noise = 0.f;
        #pragma unroll
        for (int k = 0; k < 3; ++k) {
            float2 a = pn2[r2 + k], bb = tn2[r2 + k];
            float d0 = fabsf(a.x * m - bb.x * m);
            float d1 = fabsf(a.y * m - bb.y * m);
            noise += (d0 < 1.f) ? 0.5f * d0 * d0 : d0 - 0.5f;
            noise += (d1 < 1.f) ? 0.5f * d1 * d1 : d1 - 0.5f;
        }
        s = block_sum(noise, sred); if (i == 0) ws[PB(0) + b] = s;
    } else if (chunk == 1) {
        const float2 tla = tl2[r2 + 0], tlb = tl2[r2 + 1];
        const float t0 = tla.x * m, t1 = tla.y * m,
                    t2 = tlb.x * m, t3 = tlb.y * m;
        float posmse = (p0 - t0) * (p0 - t0) + (p1 - t1) * (p1 - t1)
                     + (p2 - t2) * (p2 - t2) + (p3 - t3) * (p3 - t3);
        const float tx2 = t0 + t2, ty2 = t1 + t3;
        float iw = fmaxf(fminf(x2v, tx2) - fmaxf(p0, t0), 0.f);
        float ih = fmaxf(fminf(y2v, ty2) - fmaxf(p1, t1), 0.f);
        float inter = iw * ih;
        float iouL = 1.f - inter / (areav + t2 * t3 - inter + EPSF);
        float lmse = (p4 - t4) * (p4 - t4);
        float cmse = (p5 - t5) * (p5 - t5);
        s = block_sum(posmse, sred); if (i == 0) ws[PB(1) + b] = s;
        s = block_sum(iouL,   sred); if (i == 0) ws[PB(2) + b] = s;
        s = block_sum(lmse,   sred); if (i == 0) ws[PB(3) + b] = s;
        s = block_sum(cmse,   sred); if (i == 0) ws[PB(4) + b] = s;
    } else if (chunk == 2) {
        float golden = fabsf(p2 / (p3 + EPSF) - 1.618f);
        float areaA  = areav * m;
        s = block_sum(golden, sred);        if (i == 0) ws[PB(5) + b] = s;
        s = block_sum(areaA,  sred);        if (i == 0) ws[PB(6) + b] = s;
        s = block_sum(areaA * areaA, sred); if (i == 0) ws[PB(7) + b] = s;
    } else {
        float cxA = cxe * m, cyA = cye * m;
        s = block_sum(cxA, sred); if (i == 0) ws[PB(8)  + b] = s;
        s = block_sum(cyA, sred); if (i == 0) ws[PB(9)  + b] = s;
        s = block_sum(m,   sred); if (i == 0) ws[PB(10) + b] = s;
    }
}

__global__ __launch_bounds__(256) void loss_final(
    const float* __restrict__ ws, float* __restrict__ out)
{
    __shared__ float sred[4];
    __shared__ float bcx[NB], bcy[NB], bvc[NB];
    const int t = threadIdx.x;

    float v_noise = 0.f, v_pos = 0.f, v_iou = 0.f, v_lm = 0.f, v_cf = 0.f,
          v_go = 0.f, v_ar = 0.f, v_std = 0.f;
    if (t < NB) {
        v_noise = ws[PB(0) + t];
        v_pos   = ws[PB(1) + t];
        v_iou   = ws[PB(2) + t];
        v_lm    = ws[PB(3) + t];
        v_cf    = ws[PB(4) + t];
        v_go    = ws[PB(5) + t];
        v_ar    = ws[PB(6) + t];
        float a2 = ws[PB(7) + t];
        // per-row std, ddof=1
        float var = (a2 - v_ar * v_ar * (1.f / 256.f)) * (1.f / 255.f);
        v_std = sqrtf(fmaxf(var, 0.f));
        bcx[t] = ws[PB(8) + t];
        bcy[t] = ws[PB(9) + t];
        bvc[t] = ws[PB(10) + t];
    }
    float v_rank = ws[PW(0) + t];
    float v_ovl  = ws[PW(1) + t];
    float v_aln  = ws[PW(2) + t];
    __syncthreads();

    // faithful [B,B] balance broadcast: ocx[i,j] = sumcx[j]/(vc[i]+EPS)
    float v_bal = 0.f;
    if (t < NB) {
        float inv = 1.f / (bvc[t] + EPSF);
        for (int j = 0; j < NB; ++j) {
            v_bal += fabsf(bcx[j] * inv - 512.f) * (1.f / 512.f)
                   + fabsf(bcy[j] * inv - 512.f) * (1.f / 512.f);
        }
    }

    float S_noise = block_sum(v_noise, sred);
    float S_pos   = block_sum(v_pos,   sred);
    float S_iou   = block_sum(v_iou,   sred);
    float S_lm    = block_sum(v_lm,    sred);
    float S_cf    = block_sum(v_cf,    sred);
    float S_go    = block_sum(v_go,    sred);
    float S_ar    = block_sum(v_ar,    sred);
    float S_std   = block_sum(v_std,   sred);
    float S_bal   = block_sum(v_bal,   sred);
    float S_rank  = block_sum(v_rank,  sred);
    float S_ovl   = block_sum(v_ovl,   sred);
    float S_aln   = block_sum(v_aln,   sred);

    if (t == 0) {
        const float BN = 64.f * 256.f;
        float noise_loss = S_noise / (BN * 6.f);
        float position   = S_pos / (BN * 4.f) + 0.5f * (S_iou / BN);
        float layer      = S_lm / BN + 0.3f * (S_rank / (64.f * NPAIRS));
        float conf       = S_cf / BN;
        float golden     = S_go / BN;
        float size_harm  = (S_std / 64.f) / (S_ar / BN + EPSF);
        float balance    = S_bal / 4096.f;
        float aes        = 0.1f * golden + 0.2f * size_harm + 0.15f * balance;
        float ovl        = S_ovl / (64.f * NPAIRS);
        float aln        = S_aln / (64.f * 6.f * NPAIRS);
        out[0] = noise_loss + position + 0.5f * layer + 0.3f * conf
               + 0.2f * aes + 0.8f * ovl + 0.4f * aln;
    }
}

extern "C" void kernel_launch(void* const* d_in, const int* in_sizes, int n_in,
                              void* d_out, int out_size, void* d_ws, size_t ws_size,
                              hipStream_t stream) {
    const float* pn   = (const float*)d_in[0];
    const float* tn   = (const float*)d_in[1];
    const float* pl   = (const float*)d_in[2];
    const float* tl   = (const float*)d_in[3];
    const float* mask = (const float*)d_in[4];
    float* ws  = (float*)d_ws;
    float* out = (float*)d_out;
    hipLaunchKernelGGL(loss_main, dim3(256), dim3(256), 0, stream,
                       pn, tn, pl, tl, mask, ws);
    hipLaunchKernelGGL(loss_final, dim3(1), dim3(256), 0, stream, ws, out);
}

// Round 3
// 74.891 us; speedup vs baseline: 1.1405x; 1.0130x over previous
//
#include <hip/hip_runtime.h>
#include <math.h>

#define NB 64      // batch
#define NN 256     // elements per batch
#define NPAIRS 32640.0f   // N*(N-1)/2
#define EPSF 1e-8f

// ws layout (floats):
//   per-batch  [11][64]  at 0    : 0 noise,1 posmse,2 iou,3 layermse,4 conf,
//                                  5 golden,6 areaSum,7 area2Sum,8 cxSum,9 cySum,10 vc
//   per-block  [3][512]  at 704  : 0 rank, 1 overlap, 2 align
#define PB(q) ((q) * 64)
#define PW(q) (704 + (q) * 512)

// Block-wide sum for 256 threads (4 waves of 64). Result valid on ALL threads.
__device__ __forceinline__ float block_sum(float v, float* sred) {
    const int tid = threadIdx.x;
    #pragma unroll
    for (int off = 32; off > 0; off >>= 1) v += __shfl_down(v, off, 64);
    __syncthreads();                 // previous readers of sred are done
    if ((tid & 63) == 0) sred[tid >> 6] = v;
    __syncthreads();
    return sred[0] + sred[1] + sred[2] + sred[3];
}

__global__ __launch_bounds__(256) void loss_main(
    const float* __restrict__ pn, const float* __restrict__ tn,
    const float* __restrict__ pl, const float* __restrict__ tl,
    const float* __restrict__ mask, float* __restrict__ ws)
{
    // packed pair fields: sA = {x1, y1, x2, y2}, sB = {cx, cy, area, p_layer},
    // sC = {t_layer, m}
    __shared__ float4 sA[NN], sB[NN];
    __shared__ float2 sC[NN];
    __shared__ float sred[4];

    const int b     = blockIdx.x >> 3;   // batch
    const int chunk = blockIdx.x & 7;    // pair-distance chunk / scalar-duty chunk
    const int i     = threadIdx.x;       // element within batch
    const int e     = b * NN + i;
    const float m   = mask[e];

    // vectorized row loads (rows are 24B-aligned -> float2 ok)
    const float2* pl2 = (const float2*)pl;
    const float2* tl2 = (const float2*)tl;
    const int r2 = e * 3;
    const float2 pla = pl2[r2 + 0], plb = pl2[r2 + 1], plc = pl2[r2 + 2];
    const float2 tlc = tl2[r2 + 2];

    const float p0 = pla.x * m, p1 = pla.y * m,
                p2 = plb.x * m, p3 = plb.y * m,
                p4 = plc.x * m, p5 = plc.y * m;
    const float t4 = tlc.x * m, t5 = tlc.y * m;

    const float x2v = p0 + p2, y2v = p1 + p3;
    const float areav = p2 * p3;
    const float cxe = p0 + 0.5f * p2, cye = p1 + 0.5f * p3;

    sA[i] = make_float4(p0, p1, x2v, y2v);
    sB[i] = make_float4(cxe, cye, areav, p4);
    sC[i] = make_float2(t4, m);
    __syncthreads();

    // ---------------- pairwise terms (this chunk's 16-dd range) -------------
    float rank = 0.f, ovl = 0.f, aln = 0.f;
    const int dd0 = chunk * 16 + 1;
    #pragma unroll 8
    for (int dd = dd0; dd < dd0 + 16; ++dd) {
        int j = (i + dd) & 255;
        if (dd == 128 && i >= 128) continue;   // dd=128 pairs counted once (i<j)
        float4 aj = sA[j];
        float4 bj = sB[j];
        float2 cj = sC[j];
        float pv = m * cj.y;
        // overlap
        float ow = fmaxf(fminf(x2v, aj.z) - fmaxf(p0, aj.x), 0.f);
        float oh = fmaxf(fminf(y2v, aj.w) - fmaxf(p1, aj.y), 0.f);
        ovl += ow * oh / (fminf(areav, bj.z) + EPSF) * pv;
        // alignment (6 edge types, dist<5 -> dist/5; /5 folded into 0.2f)
        float pen = 0.f, d;
        d = fabsf(p0  - aj.x); pen += (d < 5.f) ? d : 0.f;
        d = fabsf(x2v - aj.z); pen += (d < 5.f) ? d : 0.f;
        d = fabsf(p1  - aj.y); pen += (d < 5.f) ? d : 0.f;
        d = fabsf(y2v - aj.w); pen += (d < 5.f) ? d : 0.f;
        d = fabsf(cxe - bj.x); pen += (d < 5.f) ? d : 0.f;
        d = fabsf(cye - bj.y); pen += (d < 5.f) ? d : 0.f;
        aln += pen * 0.2f * pv;
        // ranking BCE on ordered (lo,hi)=(min(i,j),max(i,j)): diff = p[hi]-p[lo]
        bool ilt = (i < j);
        float dlo = ilt ? (bj.w - p4) : (p4 - bj.w);
        float ylo = (ilt ? (t4 < cj.x) : (cj.x < t4)) ? 1.f : 0.f;
        float sp  = __logf(1.f + __expf(-fabsf(dlo)));   // stable softplus core
        float sp_pos = sp + fmaxf(dlo, 0.f);             // softplus(+diff)
        float sp_neg = sp + fmaxf(-dlo, 0.f);            // softplus(-diff)
        rank += ylo * fminf(sp_neg, 100.f) + (1.f - ylo) * fminf(sp_pos, 100.f);
    }

    // pairwise per-block sums (all chunks)
    float s;
    s = block_sum(rank, sred); if (i == 0) ws[PW(0) + blockIdx.x] = s;
    s = block_sum(ovl,  sred); if (i == 0) ws[PW(1) + blockIdx.x] = s;
    s = block_sum(aln,  sred); if (i == 0) ws[PW(2) + blockIdx.x] = s;

    // ---------------- elementwise terms: distributed across 8 chunks --------
    switch (chunk) {
    case 0: {
        // noise SmoothL1 (only this chunk touches pn/tn)
        const float2* pn2 = (const float2*)pn;
        const float2* tn2 = (const float2*)tn;
        float noise = 0.f;
        #pragma unroll
        for (int k = 0; k < 3; ++k) {
            float2 a = pn2[r2 + k], bb = tn2[r2 + k];
            float d0 = fabsf(a.x * m - bb.x * m);
            float d1 = fabsf(a.y * m - bb.y * m);
            noise += (d0 < 1.f) ? 0.5f * d0 * d0 : d0 - 0.5f;
            noise += (d1 < 1.f) ? 0.5f * d1 * d1 : d1 - 0.5f;
        }
        s = block_sum(noise, sred); if (i == 0) ws[PB(0) + b] = s;
        break; }
    case 1: {
        const float2 tla = tl2[r2 + 0], tlb = tl2[r2 + 1];
        const float t0 = tla.x * m, t1 = tla.y * m,
                    t2 = tlb.x * m, t3 = tlb.y * m;
        float posmse = (p0 - t0) * (p0 - t0) + (p1 - t1) * (p1 - t1)
                     + (p2 - t2) * (p2 - t2) + (p3 - t3) * (p3 - t3);
        const float tx2 = t0 + t2, ty2 = t1 + t3;
        float iw = fmaxf(fminf(x2v, tx2) - fmaxf(p0, t0), 0.f);
        float ih = fmaxf(fminf(y2v, ty2) - fmaxf(p1, t1), 0.f);
        float inter = iw * ih;
        float iouL = 1.f - inter / (areav + t2 * t3 - inter + EPSF);
        s = block_sum(posmse, sred); if (i == 0) ws[PB(1) + b] = s;
        s = block_sum(iouL,   sred); if (i == 0) ws[PB(2) + b] = s;
        break; }
    case 2: {
        float lmse = (p4 - t4) * (p4 - t4);
        float cmse = (p5 - t5) * (p5 - t5);
        s = block_sum(lmse, sred); if (i == 0) ws[PB(3) + b] = s;
        s = block_sum(cmse, sred); if (i == 0) ws[PB(4) + b] = s;
        break; }
    case 3: {
        float golden = fabsf(p2 / (p3 + EPSF) - 1.618f);
        s = block_sum(golden, sred); if (i == 0) ws[PB(5) + b] = s;
        break; }
    case 4: {
        float areaA = areav * m;
        s = block_sum(areaA, sred); if (i == 0) ws[PB(6) + b] = s;
        break; }
    case 5: {
        float areaA = areav * m;
        s = block_sum(areaA * areaA, sred); if (i == 0) ws[PB(7) + b] = s;
        break; }
    case 6: {
        float cxA = cxe * m, cyA = cye * m;
        s = block_sum(cxA, sred); if (i == 0) ws[PB(8) + b] = s;
        s = block_sum(cyA, sred); if (i == 0) ws[PB(9) + b] = s;
        break; }
    default: {
        s = block_sum(m, sred); if (i == 0) ws[PB(10) + b] = s;
        break; }
    }
}

__global__ __launch_bounds__(256) void loss_final(
    const float* __restrict__ ws, float* __restrict__ out)
{
    __shared__ float sred[4];
    __shared__ float bcx[NB], bcy[NB], bvc[NB];
    const int t = threadIdx.x;

    float v_noise = 0.f, v_pos = 0.f, v_iou = 0.f, v_lm = 0.f, v_cf = 0.f,
          v_go = 0.f, v_ar = 0.f, v_std = 0.f;
    if (t < NB) {
        v_noise = ws[PB(0) + t];
        v_pos   = ws[PB(1) + t];
        v_iou   = ws[PB(2) + t];
        v_lm    = ws[PB(3) + t];
        v_cf    = ws[PB(4) + t];
        v_go    = ws[PB(5) + t];
        v_ar    = ws[PB(6) + t];
        float a2 = ws[PB(7) + t];
        // per-row std, ddof=1
        float var = (a2 - v_ar * v_ar * (1.f / 256.f)) * (1.f / 255.f);
        v_std = sqrtf(fmaxf(var, 0.f));
        bcx[t] = ws[PB(8) + t];
        bcy[t] = ws[PB(9) + t];
        bvc[t] = ws[PB(10) + t];
    }
    // 512 pair-partials per term, 2 per thread
    float v_rank = ws[PW(0) + t] + ws[PW(0) + 256 + t];
    float v_ovl  = ws[PW(1) + t] + ws[PW(1) + 256 + t];
    float v_aln  = ws[PW(2) + t] + ws[PW(2) + 256 + t];
    __syncthreads();

    // faithful [B,B] balance broadcast: ocx[i,j] = sumcx[j]/(vc[i]+EPS)
    float v_bal = 0.f;
    if (t < NB) {
        float inv = 1.f / (bvc[t] + EPSF);
        for (int j = 0; j < NB; ++j) {
            v_bal += fabsf(bcx[j] * inv - 512.f) * (1.f / 512.f)
                   + fabsf(bcy[j] * inv - 512.f) * (1.f / 512.f);
        }
    }

    float S_noise = block_sum(v_noise, sred);
    float S_pos   = block_sum(v_pos,   sred);
    float S_iou   = block_sum(v_iou,   sred);
    float S_lm    = block_sum(v_lm,    sred);
    float S_cf    = block_sum(v_cf,    sred);
    float S_go    = block_sum(v_go,    sred);
    float S_ar    = block_sum(v_ar,    sred);
    float S_std   = block_sum(v_std,   sred);
    float S_bal   = block_sum(v_bal,   sred);
    float S_rank  = block_sum(v_rank,  sred);
    float S_ovl   = block_sum(v_ovl,   sred);
    float S_aln   = block_sum(v_aln,   sred);

    if (t == 0) {
        const float BN = 64.f * 256.f;
        float noise_loss = S_noise / (BN * 6.f);
        float position   = S_pos / (BN * 4.f) + 0.5f * (S_iou / BN);
        float layer      = S_lm / BN + 0.3f * (S_rank / (64.f * NPAIRS));
        float conf       = S_cf / BN;
        float golden     = S_go / BN;
        float size_harm  = (S_std / 64.f) / (S_ar / BN + EPSF);
        float balance    = S_bal / 4096.f;
        float aes        = 0.1f * golden + 0.2f * size_harm + 0.15f * balance;
        float ovl        = S_ovl / (64.f * NPAIRS);
        float aln        = S_aln / (64.f * 6.f * NPAIRS);
        out[0] = noise_loss + position + 0.5f * layer + 0.3f * conf
               + 0.2f * aes + 0.8f * ovl + 0.4f * aln;
    }
}

extern "C" void kernel_launch(void* const* d_in, const int* in_sizes, int n_in,
                              void* d_out, int out_size, void* d_ws, size_t ws_size,
                              hipStream_t stream) {
    const float* pn   = (const float*)d_in[0];
    const float* tn   = (const float*)d_in[1];
    const float* pl   = (const float*)d_in[2];
    const float* tl   = (const float*)d_in[3];
    const float* mask = (const float*)d_in[4];
    float* ws  = (float*)d_ws;
    float* out = (float*)d_out;
    hipLaunchKernelGGL(loss_main, dim3(512), dim3(256), 0, stream,
                       pn, tn, pl, tl, mask, ws);
    hipLaunchKernelGGL(loss_final, dim3(1), dim3(256), 0, stream, ws, out);
}